// Round 8
// baseline (472.681 us; speedup 1.0000x reference)
//
#include <hip/hip_runtime.h>

// Problem constants
#define BB   128
#define DD   2048
#define NN   2048
#define LL   4
#define OUTN 1024
#define JBW  64                // 16-k groups per wave (K=1024 per k-half wave)

typedef double double4v __attribute__((ext_vector_type(4)));

// ---------------------------------------------------------------------------
// Layer-0 transpose-gather: At[k][b] = x[b, axon_idx0[k]]
// ---------------------------------------------------------------------------
__global__ __launch_bounds__(256) void gather0_kernel(
    const float* __restrict__ x, const int* __restrict__ idx0,
    float* __restrict__ At)
{
    int i = blockIdx.x * 256 + threadIdx.x;   // over DD*BB
    int k = i >> 7;
    int b = i & 127;
    At[i] = x[b * DD + idx0[k]];
}

// ---------------------------------------------------------------------------
// Barrier-free fused layer kernel.
// Block: 128 thr = 2 waves = 2 K-halves (wk) of ONE 16n x 16b output tile.
// Grid: 128 ntiles x 8 btiles = 1024 blocks (4/CU, 2 waves/SIMD, free-running).
// Custom k-quad assignment: at step e of group jb, lane (q,c) supplies
//   A = W[n0+c][16jb+4q+e]  (component e of a coalesced per-lane float4)
//   B = src[row(16jb+4q+e)][bcol]  (per-lane scalar, L2-resident)
// -> NO LDS staging, NO barriers in the K-loop. Register pipeline:
//   W float4 depth-4, idx int4 depth-4, src depth-2.
// Epilogue: one LDS reduce of the two K-halves + spike scan + direct store.
// D-fragment layout discovered at runtime via two probe MFMAs (R4-proven).
// ---------------------------------------------------------------------------
__global__ __launch_bounds__(128, 2) void layer_kernel(
    const float* __restrict__ srcT,   // [2048 rows][BB] fp32
    const int*   __restrict__ idx,    // nullptr => identity rows
    const float* __restrict__ Wl,     // [n][k] row-major
    const float* __restrict__ thresholds, int l,
    const int*   __restrict__ Tptr,
    float* __restrict__ dst, int isLast)
{
    __shared__ double red[256];        // 2 KB, epilogue only

    const int t    = threadIdx.x;
    const int wk   = t >> 6;           // k-half
    const int lane = t & 63;
    const int q    = lane >> 4;
    const int c    = lane & 15;

    const int g     = blockIdx.x;      // 0..1023
    const int ntile = g & 127;         // same-ntile blocks: bid stride 128 -> same XCD
    const int btile = g >> 7;          // 0..7
    const int n0    = ntile * 16;
    const int bcol  = btile * 16 + c;

    // ---- runtime D-layout probe (layout-agnostic epilogue) ----
    double4v pr = {0., 0., 0., 0.}, pcv = {0., 0., 0., 0.};
    pr  = __builtin_amdgcn_mfma_f64_16x16x4f64(0.25 * (double)c, 1.0, pr, 0, 0, 0);
    pcv = __builtin_amdgcn_mfma_f64_16x16x4f64(0.25, (double)c, pcv, 0, 0, 0);
    int rowD[4], colD[4];
    #pragma unroll
    for (int r = 0; r < 4; ++r) {
        rowD[r] = (int)(pr[r] + 0.25);
        colD[r] = (int)(pcv[r] + 0.25);
    }

    double4v acc[4] = {{0.,0.,0.,0.},{0.,0.,0.,0.},{0.,0.,0.,0.},{0.,0.,0.,0.}};

    const int    kbase = wk * (DD / 2);
    const float* wbase = Wl + (size_t)(n0 + c) * DD + kbase + 4 * q;
    const int*   ibase = idx ? (idx + kbase + 4 * q) : nullptr;

    float4 wv[4];      // W pipeline, depth 4
    int4   iv[4];      // idx pipeline, depth 4
    float  sv[2][4];   // src pipeline, depth 2

    // ---- prologue ----
    #pragma unroll
    for (int p = 0; p < 4; ++p) wv[p] = *(const float4*)(wbase + 16 * p);
    if (ibase) {
        #pragma unroll
        for (int p = 0; p < 4; ++p) iv[p] = *(const int4*)(ibase + 16 * p);
    }
    #pragma unroll
    for (int p = 0; p < 2; ++p) {
        int r0, r1, r2, r3;
        if (ibase) { r0 = iv[p].x; r1 = iv[p].y; r2 = iv[p].z; r3 = iv[p].w; }
        else { int kb = kbase + 16 * p + 4 * q; r0 = kb; r1 = kb+1; r2 = kb+2; r3 = kb+3; }
        sv[p][0] = srcT[(size_t)r0 * BB + bcol];
        sv[p][1] = srcT[(size_t)r1 * BB + bcol];
        sv[p][2] = srcT[(size_t)r2 * BB + bcol];
        sv[p][3] = srcT[(size_t)r3 * BB + bcol];
    }

    // ---- barrier-free K-loop ----
    for (int jb = 0; jb < JBW; ++jb) {
        // snapshot current operands (vmcnt waits land here: W issued jb-4,
        // src issued jb-2 -> 512-1024 cyc of slack)
        float4 wcur = wv[jb & 3];
        float  s0 = sv[jb & 1][0], s1 = sv[jb & 1][1];
        float  s2 = sv[jb & 1][2], s3 = sv[jb & 1][3];

        // refill W slot with group jb+4 (clamped: duplicate load, harmless)
        {
            int jn = jb + 4; if (jn >= JBW) jn = JBW - 1;
            wv[jb & 3] = *(const float4*)(wbase + 16 * jn);
        }
        // issue src(jb+2) using idx slot (jb+2) (loaded at jb-2, ready)
        {
            int js = jb + 2; if (js >= JBW) js = JBW - 1;
            int r0, r1, r2, r3;
            if (ibase) {
                int4 ivv = iv[js & 3];
                r0 = ivv.x; r1 = ivv.y; r2 = ivv.z; r3 = ivv.w;
            } else {
                int kb = kbase + 16 * js + 4 * q;
                r0 = kb; r1 = kb + 1; r2 = kb + 2; r3 = kb + 3;
            }
            sv[jb & 1][0] = srcT[(size_t)r0 * BB + bcol];
            sv[jb & 1][1] = srcT[(size_t)r1 * BB + bcol];
            sv[jb & 1][2] = srcT[(size_t)r2 * BB + bcol];
            sv[jb & 1][3] = srcT[(size_t)r3 * BB + bcol];
        }
        // refill idx slot with group jb+4
        if (ibase) {
            int jn = jb + 4; if (jn >= JBW) jn = JBW - 1;
            iv[jb & 3] = *(const int4*)(ibase + 16 * jn);
        }
        // 4 MFMAs, one per e-chain (dep distance 4 x 64 cyc)
        acc[0] = __builtin_amdgcn_mfma_f64_16x16x4f64((double)wcur.x, (double)s0, acc[0], 0, 0, 0);
        acc[1] = __builtin_amdgcn_mfma_f64_16x16x4f64((double)wcur.y, (double)s1, acc[1], 0, 0, 0);
        acc[2] = __builtin_amdgcn_mfma_f64_16x16x4f64((double)wcur.z, (double)s2, acc[2], 0, 0, 0);
        acc[3] = __builtin_amdgcn_mfma_f64_16x16x4f64((double)wcur.w, (double)s3, acc[3], 0, 0, 0);
    }

    // fixed-order chain merge (deterministic)
    double4v a = (acc[0] + acc[1]) + (acc[2] + acc[3]);

    // ---- K-half reduction via LDS (the only barrier) ----
    if (wk == 1) {
        #pragma unroll
        for (int r = 0; r < 4; ++r) red[lane * 4 + r] = a[r];
    }
    __syncthreads();
    if (wk == 0) {
        #pragma unroll
        for (int r = 0; r < 4; ++r) a[r] += red[lane * 4 + r];

        // ---- spike scan (4 independent chains) + direct store ----
        const double th = (double)thresholds[l];
        const int T = *Tptr;
        const float sc = isLast ? 1.0f : (1.0f / (float)T);   // cnt/T exact fp32
        double m0 = 0., m1 = 0., m2 = 0., m3 = 0.;
        int c0 = 0, c1 = 0, c2 = 0, c3 = 0;
        for (int tt = 0; tt < T; ++tt) {
            m0 += a[0]; if (m0 > th) { c0++; m0 -= th; }
            m1 += a[1]; if (m1 > th) { c1++; m1 -= th; }
            m2 += a[2]; if (m2 > th) { c2++; m2 -= th; }
            m3 += a[3]; if (m3 > th) { c3++; m3 -= th; }
        }
        int cnt[4] = {c0, c1, c2, c3};
        #pragma unroll
        for (int r = 0; r < 4; ++r) {
            int n = n0 + rowD[r];
            dst[(size_t)n * BB + btile * 16 + colD[r]] = (float)cnt[r] * sc;
        }
    }
}

// ---------------------------------------------------------------------------
// Output gather: out[b, o] = cntT[out_idx[o]][b]
// ---------------------------------------------------------------------------
__global__ __launch_bounds__(256) void out_kernel(
    const float* __restrict__ cntT, const int* __restrict__ out_idx,
    float* __restrict__ out)
{
    int i = blockIdx.x * 256 + threadIdx.x;   // over BB*OUTN
    int b = i >> 10;
    int o = i & 1023;
    out[i] = cntT[(size_t)out_idx[o] * BB + b];
}

extern "C" void kernel_launch(void* const* d_in, const int* in_sizes, int n_in,
                              void* d_out, int out_size, void* d_ws, size_t ws_size,
                              hipStream_t stream)
{
    const float* x    = (const float*)d_in[0];
    const float* W    = (const float*)d_in[1];
    const float* thr  = (const float*)d_in[2];
    const int*   axon = (const int*)d_in[3];
    const int*   oidx = (const int*)d_in[4];
    const int*   Tptr = (const int*)d_in[5];
    float* out = (float*)d_out;

    char* ws = (char*)d_ws;
    float* At   = (float*)ws;                  // 1 MB [2048][128]
    float* mA   = (float*)(ws + (1u << 20));   // 1 MB ping
    float* mB   = (float*)(ws + (2u << 20));   // 1 MB pong
    float* cntT = (float*)(ws + (3u << 20));   // 1 MB

    gather0_kernel<<<(DD * BB) / 256, 256, 0, stream>>>(x, axon, At);

    // ping-pong buffers: no in-place read/write hazard within a layer
    const float* srcs[LL] = { At, mA, mB, mA };
    float*       dsts[LL] = { mA, mB, mA, cntT };
    for (int l = 0; l < LL; ++l) {
        const int* idx = (l == 0) ? nullptr : (axon + (size_t)l * DD);
        layer_kernel<<<1024, 128, 0, stream>>>(
            srcs[l], idx, W + (size_t)l * NN * DD, thr, l, Tptr,
            dsts[l], (l == LL - 1) ? 1 : 0);
    }

    out_kernel<<<(BB * OUTN) / 256, 256, 0, stream>>>(cntT, oidx, out);
}

// Round 9
// 240.961 us; speedup vs baseline: 1.9617x; 1.9617x over previous
//
#include <hip/hip_runtime.h>

// Problem constants
#define BB   128
#define DD   2048
#define NN   2048
#define LL   4
#define OUTN 1024
#define JBW  64                // 16-k groups per wave (K=1024 per k-half wave)

typedef double double4v __attribute__((ext_vector_type(4)));

// ---------------------------------------------------------------------------
// Layer-0 transpose-gather: At[k][b] = x[b, axon_idx0[k]]
// ---------------------------------------------------------------------------
__global__ __launch_bounds__(256) void gather0_kernel(
    const float* __restrict__ x, const int* __restrict__ idx0,
    float* __restrict__ At)
{
    int i = blockIdx.x * 256 + threadIdx.x;   // over DD*BB
    int k = i >> 7;
    int b = i & 127;
    At[i] = x[b * DD + idx0[k]];
}

// ---------------------------------------------------------------------------
// Barrier-free fused layer kernel (R8 structure, spill-free).
// Block: 128 thr = 2 waves = 2 K-halves (wk) of ONE 16n x 16b output tile.
// Grid: 128 ntiles x 8 btiles = 1024 blocks (4/CU, 2 waves/SIMD).
// k-slot assignment: at step e of group jb, lane (q,c) supplies
//   A = W[n0+c][16jb+4q+e]   (component e of a coalesced per-lane float4)
//   B = src[row(16jb+4q+e)][bcol]
// K-loop UNROLLED BY 4: pipeline slots wv[g]/iv[g]/sv[g] have static indices
// -> stay in VGPRs (R8's dynamic jb&3 indexing demoted them to LDS/scratch:
//    VGPR 44, LDS 10 KB, 23 MB scratch writes, 4.9M bank conflicts).
// Epilogue: one LDS reduce of the two K-halves + spike scan + direct store.
// D-fragment layout discovered at runtime via two probe MFMAs (R4-proven).
// ---------------------------------------------------------------------------
__global__ __launch_bounds__(128, 2) void layer_kernel(
    const float* __restrict__ srcT,   // [2048 rows][BB] fp32
    const int*   __restrict__ idx,    // nullptr => identity rows
    const float* __restrict__ Wl,     // [n][k] row-major
    const float* __restrict__ thresholds, int l,
    const int*   __restrict__ Tptr,
    float* __restrict__ dst, int isLast)
{
    __shared__ double red[256];        // 2 KB, epilogue only

    const int t    = threadIdx.x;
    const int wk   = t >> 6;           // k-half
    const int lane = t & 63;
    const int q    = lane >> 4;
    const int c    = lane & 15;

    const int g     = blockIdx.x;      // 0..1023
    const int ntile = g & 127;         // same-ntile blocks: bid stride 128 -> same XCD
    const int btile = g >> 7;          // 0..7
    const int n0    = ntile * 16;
    const int bcol  = btile * 16 + c;

    // ---- runtime D-layout probe (layout-agnostic epilogue) ----
    double4v pr = {0., 0., 0., 0.}, pcv = {0., 0., 0., 0.};
    pr  = __builtin_amdgcn_mfma_f64_16x16x4f64(0.25 * (double)c, 1.0, pr, 0, 0, 0);
    pcv = __builtin_amdgcn_mfma_f64_16x16x4f64(0.25, (double)c, pcv, 0, 0, 0);
    int rowD[4], colD[4];
    #pragma unroll
    for (int r = 0; r < 4; ++r) {
        rowD[r] = (int)(pr[r] + 0.25);
        colD[r] = (int)(pcv[r] + 0.25);
    }

    double4v acc[4] = {{0.,0.,0.,0.},{0.,0.,0.,0.},{0.,0.,0.,0.},{0.,0.,0.,0.}};

    const int    kbase = wk * (DD / 2);
    const float* wbase = Wl + (size_t)(n0 + c) * DD + kbase + 4 * q;
    const int*   ibase = idx ? (idx + kbase + 4 * q) : nullptr;

    float4 wv[4];      // W pipeline (group 4u+g), static slots
    int4   iv[4];      // idx pipeline (group 4u+4+g), static slots
    float4 sv[4];      // src pipeline (group 4u+g), static slots

    // ---- prologue ----
    #pragma unroll
    for (int p = 0; p < 4; ++p) wv[p] = *(const float4*)(wbase + 16 * p);
    #pragma unroll
    for (int p = 0; p < 4; ++p) {
        int r0, r1, r2, r3;
        if (ibase) {
            int4 iv0 = *(const int4*)(ibase + 16 * p);
            r0 = iv0.x; r1 = iv0.y; r2 = iv0.z; r3 = iv0.w;
        } else {
            int kb = kbase + 16 * p + 4 * q;
            r0 = kb; r1 = kb + 1; r2 = kb + 2; r3 = kb + 3;
        }
        sv[p].x = srcT[(size_t)r0 * BB + bcol];
        sv[p].y = srcT[(size_t)r1 * BB + bcol];
        sv[p].z = srcT[(size_t)r2 * BB + bcol];
        sv[p].w = srcT[(size_t)r3 * BB + bcol];
    }
    if (ibase) {
        #pragma unroll
        for (int p = 0; p < 4; ++p) iv[p] = *(const int4*)(ibase + 16 * (4 + p));
    }

    // ---- barrier-free K-loop: 16 iterations x 4 static-slot groups ----
    for (int u = 0; u < JBW / 4; ++u) {
        #pragma unroll
        for (int gg = 0; gg < 4; ++gg) {
            float4 wcur = wv[gg];
            float4 scur = sv[gg];

            // refill W slot with group jn = 4u+4+gg (clamped dup at tail)
            int jn = 4 * u + 4 + gg; if (jn > JBW - 1) jn = JBW - 1;
            wv[gg] = *(const float4*)(wbase + 16 * jn);

            // issue src for group jn using iv[gg] (holds idx of group jn)
            int r0, r1, r2, r3;
            if (ibase) {
                int4 ivv = iv[gg];
                r0 = ivv.x; r1 = ivv.y; r2 = ivv.z; r3 = ivv.w;
            } else {
                int kb = kbase + 16 * jn + 4 * q;
                r0 = kb; r1 = kb + 1; r2 = kb + 2; r3 = kb + 3;
            }
            sv[gg].x = srcT[(size_t)r0 * BB + bcol];
            sv[gg].y = srcT[(size_t)r1 * BB + bcol];
            sv[gg].z = srcT[(size_t)r2 * BB + bcol];
            sv[gg].w = srcT[(size_t)r3 * BB + bcol];

            // refill idx slot with group 4u+8+gg
            if (ibase) {
                int jm = 4 * u + 8 + gg; if (jm > JBW - 1) jm = JBW - 1;
                iv[gg] = *(const int4*)(ibase + 16 * jm);
            }

            // 4 MFMAs, one per e-chain (dep distance 4 groups x 64 cyc)
            acc[0] = __builtin_amdgcn_mfma_f64_16x16x4f64((double)wcur.x, (double)scur.x, acc[0], 0, 0, 0);
            acc[1] = __builtin_amdgcn_mfma_f64_16x16x4f64((double)wcur.y, (double)scur.y, acc[1], 0, 0, 0);
            acc[2] = __builtin_amdgcn_mfma_f64_16x16x4f64((double)wcur.z, (double)scur.z, acc[2], 0, 0, 0);
            acc[3] = __builtin_amdgcn_mfma_f64_16x16x4f64((double)wcur.w, (double)scur.w, acc[3], 0, 0, 0);
        }
    }

    // fixed-order chain merge (deterministic)
    double4v a = (acc[0] + acc[1]) + (acc[2] + acc[3]);

    // ---- K-half reduction via LDS (the only barrier) ----
    if (wk == 1) {
        #pragma unroll
        for (int r = 0; r < 4; ++r) red[lane * 4 + r] = a[r];
    }
    __syncthreads();
    if (wk == 0) {
        #pragma unroll
        for (int r = 0; r < 4; ++r) a[r] += red[lane * 4 + r];

        // ---- spike scan (4 independent chains) + direct store ----
        const double th = (double)thresholds[l];
        const int T = *Tptr;
        const float sc = isLast ? 1.0f : (1.0f / (float)T);   // cnt/T exact fp32
        double m0 = 0., m1 = 0., m2 = 0., m3 = 0.;
        int c0 = 0, c1 = 0, c2 = 0, c3 = 0;
        for (int tt = 0; tt < T; ++tt) {
            m0 += a[0]; if (m0 > th) { c0++; m0 -= th; }
            m1 += a[1]; if (m1 > th) { c1++; m1 -= th; }
            m2 += a[2]; if (m2 > th) { c2++; m2 -= th; }
            m3 += a[3]; if (m3 > th) { c3++; m3 -= th; }
        }
        int cnt[4] = {c0, c1, c2, c3};
        #pragma unroll
        for (int r = 0; r < 4; ++r) {
            int n = n0 + rowD[r];
            dst[(size_t)n * BB + btile * 16 + colD[r]] = (float)cnt[r] * sc;
        }
    }
}

// ---------------------------------------------------------------------------
// Output gather: out[b, o] = cntT[out_idx[o]][b]
// ---------------------------------------------------------------------------
__global__ __launch_bounds__(256) void out_kernel(
    const float* __restrict__ cntT, const int* __restrict__ out_idx,
    float* __restrict__ out)
{
    int i = blockIdx.x * 256 + threadIdx.x;   // over BB*OUTN
    int b = i >> 10;
    int o = i & 1023;
    out[i] = cntT[(size_t)out_idx[o] * BB + b];
}

extern "C" void kernel_launch(void* const* d_in, const int* in_sizes, int n_in,
                              void* d_out, int out_size, void* d_ws, size_t ws_size,
                              hipStream_t stream)
{
    const float* x    = (const float*)d_in[0];
    const float* W    = (const float*)d_in[1];
    const float* thr  = (const float*)d_in[2];
    const int*   axon = (const int*)d_in[3];
    const int*   oidx = (const int*)d_in[4];
    const int*   Tptr = (const int*)d_in[5];
    float* out = (float*)d_out;

    char* ws = (char*)d_ws;
    float* At   = (float*)ws;                  // 1 MB [2048][128]
    float* mA   = (float*)(ws + (1u << 20));   // 1 MB ping
    float* mB   = (float*)(ws + (2u << 20));   // 1 MB pong
    float* cntT = (float*)(ws + (3u << 20));   // 1 MB

    gather0_kernel<<<(DD * BB) / 256, 256, 0, stream>>>(x, axon, At);

    // ping-pong buffers: no in-place read/write hazard within a layer
    const float* srcs[LL] = { At, mA, mB, mA };
    float*       dsts[LL] = { mA, mB, mA, cntT };
    for (int l = 0; l < LL; ++l) {
        const int* idx = (l == 0) ? nullptr : (axon + (size_t)l * DD);
        layer_kernel<<<1024, 128, 0, stream>>>(
            srcs[l], idx, W + (size_t)l * NN * DD, thr, l, Tptr,
            dsts[l], (l == LL - 1) ? 1 : 0);
    }

    out_kernel<<<(BB * OUTN) / 256, 256, 0, stream>>>(cntT, oidx, out);
}

// Round 10
// 227.580 us; speedup vs baseline: 2.0770x; 1.0588x over previous
//
#include <hip/hip_runtime.h>

// Problem constants
#define BB   128
#define DD   2048
#define NN   2048
#define LL   4
#define OUTN 1024
#define JBQ  32                // 16-k groups per K-quarter (512 k / quarter)

typedef double double4v __attribute__((ext_vector_type(4)));

// ---------------------------------------------------------------------------
// Layer-0 transpose-gather: At[k][b] = x[b, axon_idx0[k]]
// ---------------------------------------------------------------------------
__global__ __launch_bounds__(256) void gather0_kernel(
    const float* __restrict__ x, const int* __restrict__ idx0,
    float* __restrict__ At)
{
    int i = blockIdx.x * 256 + threadIdx.x;   // over DD*BB
    int k = i >> 7;
    int b = i & 127;
    At[i] = x[b * DD + idx0[k]];
}

// ---------------------------------------------------------------------------
// Barrier-free fused layer kernel, v2: wave tile 32n x 16b (2 n-tiles share
// the B operand -> 8 MFMAs per group amortize one set of loads/addr/cvt).
// Block: 256 thr = 4 waves = 4 K-quarters (512 k each) of one 32n x 16b tile.
// Grid: 64 nsup x 8 btiles = 512 blocks (2/CU, 2 waves/SIMD).
// k-slot assignment (R9-proven): at step e of group jb, lane (q,c) supplies
//   A0 = W[n0+c][16jb+4q+e], A1 = W[n0+16+c][16jb+4q+e]  (float4 components)
//   B  = src[row(16jb+4q+e)][bcol]
// K-loop unrolled by 4 -> all pipeline slots statically indexed (no spills).
// Swizzle: the 8 b-replicas of one nsup land on one XCD (W L2-resident).
// Epilogue: LDS reduce of 4 quarters (fixed order) + spike scan + store.
// D-fragment layout discovered at runtime via two probe MFMAs (R4-proven).
// ---------------------------------------------------------------------------
__global__ __launch_bounds__(256, 2) void layer_kernel(
    const float* __restrict__ srcT,   // [2048 rows][BB] fp32
    const int*   __restrict__ idx,    // nullptr => identity rows
    const float* __restrict__ Wl,     // [n][k] row-major
    const float* __restrict__ thresholds, int l,
    const int*   __restrict__ Tptr,
    float* __restrict__ dst, int isLast)
{
    __shared__ double red[4 * 64 * 8];   // 16 KB, epilogue only

    const int t    = threadIdx.x;
    const int wq   = t >> 6;             // K-quarter 0..3
    const int lane = t & 63;
    const int q    = lane >> 4;
    const int c    = lane & 15;

    const int g     = blockIdx.x;        // 0..511
    const int btile = (g >> 3) & 7;      // b-replicas of one nsup: same XCD (mod 8)
    const int nsup  = (g & 7) | ((g >> 6) << 3);
    const int n0    = nsup * 32;
    const int bcol  = btile * 16 + c;

    // ---- runtime D-layout probe (layout-agnostic epilogue) ----
    double4v pr = {0., 0., 0., 0.}, pcv = {0., 0., 0., 0.};
    pr  = __builtin_amdgcn_mfma_f64_16x16x4f64(0.25 * (double)c, 1.0, pr, 0, 0, 0);
    pcv = __builtin_amdgcn_mfma_f64_16x16x4f64(0.25, (double)c, pcv, 0, 0, 0);
    int rowD[4], colD[4];
    #pragma unroll
    for (int r = 0; r < 4; ++r) {
        rowD[r] = (int)(pr[r] + 0.25);
        colD[r] = (int)(pcv[r] + 0.25);
    }

    double4v acc0[4] = {{0.,0.,0.,0.},{0.,0.,0.,0.},{0.,0.,0.,0.},{0.,0.,0.,0.}};
    double4v acc1[4] = {{0.,0.,0.,0.},{0.,0.,0.,0.},{0.,0.,0.,0.},{0.,0.,0.,0.}};

    const int    kbase = wq * (DD / 4);  // 512 k per quarter
    const float* wb0   = Wl + (size_t)(n0 + c) * DD + kbase + 4 * q;
    const float* wb1   = wb0 + (size_t)16 * DD;
    const int*   ibase = idx ? (idx + kbase + 4 * q) : nullptr;

    float4 wv0[4], wv1[4];   // W pipelines (2 n-rows), static slots
    float4 sv[4];            // src pipeline, static slots
    int4   iv[4];            // idx pipeline, static slots

    // ---- prologue: groups 0..3 ----
    #pragma unroll
    for (int p = 0; p < 4; ++p) {
        wv0[p] = *(const float4*)(wb0 + 16 * p);
        wv1[p] = *(const float4*)(wb1 + 16 * p);
    }
    #pragma unroll
    for (int p = 0; p < 4; ++p) {
        int r0, r1, r2, r3;
        if (ibase) {
            int4 iv0 = *(const int4*)(ibase + 16 * p);
            r0 = iv0.x; r1 = iv0.y; r2 = iv0.z; r3 = iv0.w;
        } else {
            int kb = kbase + 16 * p + 4 * q;
            r0 = kb; r1 = kb + 1; r2 = kb + 2; r3 = kb + 3;
        }
        sv[p].x = srcT[(size_t)r0 * BB + bcol];
        sv[p].y = srcT[(size_t)r1 * BB + bcol];
        sv[p].z = srcT[(size_t)r2 * BB + bcol];
        sv[p].w = srcT[(size_t)r3 * BB + bcol];
    }
    if (ibase) {
        #pragma unroll
        for (int p = 0; p < 4; ++p) iv[p] = *(const int4*)(ibase + 16 * (4 + p));
    }

    // ---- barrier-free K-loop: 8 iterations x 4 static-slot groups ----
    for (int u = 0; u < JBQ / 4; ++u) {
        #pragma unroll
        for (int gg = 0; gg < 4; ++gg) {
            float4 w0 = wv0[gg];
            float4 w1 = wv1[gg];
            float4 s  = sv[gg];

            // refill W slots with group jn = 4u+4+gg (clamped dup at tail)
            int jn = 4 * u + 4 + gg; if (jn > JBQ - 1) jn = JBQ - 1;
            wv0[gg] = *(const float4*)(wb0 + 16 * jn);
            wv1[gg] = *(const float4*)(wb1 + 16 * jn);

            // issue src for group jn using iv[gg] (holds idx of group jn)
            int r0, r1, r2, r3;
            if (ibase) {
                int4 ivv = iv[gg];
                r0 = ivv.x; r1 = ivv.y; r2 = ivv.z; r3 = ivv.w;
            } else {
                int kb = kbase + 16 * jn + 4 * q;
                r0 = kb; r1 = kb + 1; r2 = kb + 2; r3 = kb + 3;
            }
            sv[gg].x = srcT[(size_t)r0 * BB + bcol];
            sv[gg].y = srcT[(size_t)r1 * BB + bcol];
            sv[gg].z = srcT[(size_t)r2 * BB + bcol];
            sv[gg].w = srcT[(size_t)r3 * BB + bcol];

            // refill idx slot with group 4u+8+gg
            if (ibase) {
                int jm = 4 * u + 8 + gg; if (jm > JBQ - 1) jm = JBQ - 1;
                iv[gg] = *(const int4*)(ibase + 16 * jm);
            }

            // 8 MFMAs: 2 n-tiles x 4 e-chains, shared B
            acc0[0] = __builtin_amdgcn_mfma_f64_16x16x4f64((double)w0.x, (double)s.x, acc0[0], 0, 0, 0);
            acc1[0] = __builtin_amdgcn_mfma_f64_16x16x4f64((double)w1.x, (double)s.x, acc1[0], 0, 0, 0);
            acc0[1] = __builtin_amdgcn_mfma_f64_16x16x4f64((double)w0.y, (double)s.y, acc0[1], 0, 0, 0);
            acc1[1] = __builtin_amdgcn_mfma_f64_16x16x4f64((double)w1.y, (double)s.y, acc1[1], 0, 0, 0);
            acc0[2] = __builtin_amdgcn_mfma_f64_16x16x4f64((double)w0.z, (double)s.z, acc0[2], 0, 0, 0);
            acc1[2] = __builtin_amdgcn_mfma_f64_16x16x4f64((double)w1.z, (double)s.z, acc1[2], 0, 0, 0);
            acc0[3] = __builtin_amdgcn_mfma_f64_16x16x4f64((double)w0.w, (double)s.w, acc0[3], 0, 0, 0);
            acc1[3] = __builtin_amdgcn_mfma_f64_16x16x4f64((double)w1.w, (double)s.w, acc1[3], 0, 0, 0);
        }
    }

    // fixed-order chain merge (deterministic)
    double4v a0 = (acc0[0] + acc0[1]) + (acc0[2] + acc0[3]);
    double4v a1 = (acc1[0] + acc1[1]) + (acc1[2] + acc1[3]);

    // ---- K-quarter reduction via LDS (single barrier, fixed order) ----
    {
        double* my = red + ((size_t)wq * 64 + lane) * 8;
        #pragma unroll
        for (int r = 0; r < 4; ++r) { my[r] = a0[r]; my[4 + r] = a1[r]; }
    }
    __syncthreads();
    if (wq < 2) {
        // wave 0 -> n-tile 0 (offset 0), wave 1 -> n-tile 1 (offset 4)
        const int off = wq * 4;
        double a[4];
        #pragma unroll
        for (int r = 0; r < 4; ++r) {
            a[r] =  red[((size_t)0 * 64 + lane) * 8 + off + r];
            a[r] += red[((size_t)1 * 64 + lane) * 8 + off + r];
            a[r] += red[((size_t)2 * 64 + lane) * 8 + off + r];
            a[r] += red[((size_t)3 * 64 + lane) * 8 + off + r];
        }

        // ---- spike scan (4 independent chains) + direct store ----
        const double th = (double)thresholds[l];
        const int T = *Tptr;
        const float sc = isLast ? 1.0f : (1.0f / (float)T);   // cnt/T exact fp32
        double m0 = 0., m1 = 0., m2 = 0., m3 = 0.;
        int c0 = 0, c1 = 0, c2 = 0, c3 = 0;
        for (int tt = 0; tt < T; ++tt) {
            m0 += a[0]; if (m0 > th) { c0++; m0 -= th; }
            m1 += a[1]; if (m1 > th) { c1++; m1 -= th; }
            m2 += a[2]; if (m2 > th) { c2++; m2 -= th; }
            m3 += a[3]; if (m3 > th) { c3++; m3 -= th; }
        }
        int cnt[4] = {c0, c1, c2, c3};
        #pragma unroll
        for (int r = 0; r < 4; ++r) {
            int n = n0 + 16 * wq + rowD[r];
            dst[(size_t)n * BB + btile * 16 + colD[r]] = (float)cnt[r] * sc;
        }
    }
}

// ---------------------------------------------------------------------------
// Output gather: out[b, o] = cntT[out_idx[o]][b]
// ---------------------------------------------------------------------------
__global__ __launch_bounds__(256) void out_kernel(
    const float* __restrict__ cntT, const int* __restrict__ out_idx,
    float* __restrict__ out)
{
    int i = blockIdx.x * 256 + threadIdx.x;   // over BB*OUTN
    int b = i >> 10;
    int o = i & 1023;
    out[i] = cntT[(size_t)out_idx[o] * BB + b];
}

extern "C" void kernel_launch(void* const* d_in, const int* in_sizes, int n_in,
                              void* d_out, int out_size, void* d_ws, size_t ws_size,
                              hipStream_t stream)
{
    const float* x    = (const float*)d_in[0];
    const float* W    = (const float*)d_in[1];
    const float* thr  = (const float*)d_in[2];
    const int*   axon = (const int*)d_in[3];
    const int*   oidx = (const int*)d_in[4];
    const int*   Tptr = (const int*)d_in[5];
    float* out = (float*)d_out;

    char* ws = (char*)d_ws;
    float* At   = (float*)ws;                  // 1 MB [2048][128]
    float* mA   = (float*)(ws + (1u << 20));   // 1 MB ping
    float* mB   = (float*)(ws + (2u << 20));   // 1 MB pong
    float* cntT = (float*)(ws + (3u << 20));   // 1 MB

    gather0_kernel<<<(DD * BB) / 256, 256, 0, stream>>>(x, axon, At);

    // ping-pong buffers: no in-place read/write hazard within a layer
    const float* srcs[LL] = { At, mA, mB, mA };
    float*       dsts[LL] = { mA, mB, mA, cntT };
    for (int l = 0; l < LL; ++l) {
        const int* idx = (l == 0) ? nullptr : (axon + (size_t)l * DD);
        layer_kernel<<<512, 256, 0, stream>>>(
            srcs[l], idx, W + (size_t)l * NN * DD, thr, l, Tptr,
            dsts[l], (l == LL - 1) ? 1 : 0);
    }

    out_kernel<<<(BB * OUTN) / 256, 256, 0, stream>>>(cntT, oidx, out);
}